// Round 2
// baseline (171.962 us; speedup 1.0000x reference)
//
#include <hip/hip_runtime.h>
#include <stdint.h>

// Problem geometry (fixed by the reference): A bits [4,512,512,32], B bits [512,512,32]
#define BATCH 4
#define MDIM  512
#define KDIM  512
#define NDIM  512
#define BM    8          // rows of C per block in the GEMM

// ---------------------------------------------------------------------------
// Kernel 1/2: pulse bits (float {0,1}, bit 0 = LSB) -> uint32 words.
// Thread g reads bit g (fully coalesced). A 64-lane wave covers exactly two
// fp32 words; __ballot assembles both at once (bit L of mask = lane L's pred).
// ---------------------------------------------------------------------------
__global__ void decode_bits_kernel(const float* __restrict__ bits,
                                   uint32_t* __restrict__ words, int nbits) {
    int g = blockIdx.x * blockDim.x + threadIdx.x;
    if (g >= nbits) return;
    float v = bits[g];
    unsigned long long mask = __ballot(v != 0.0f);
    int lane = threadIdx.x & 63;
    if ((lane & 31) == 0) {
        uint32_t w = (lane == 0) ? (uint32_t)mask : (uint32_t)(mask >> 32);
        words[g >> 5] = w;
    }
}

// ---------------------------------------------------------------------------
// Kernel 3: fp32 GEMM matching np.einsum('bmk,kn->bmn', optimize=False):
// per output element, STRICT sequential accumulation over k ascending, one
// FMA per step (numpy's npyv_muladd axpy loop on AVX2/512 hosts):
//   acc = fma(A[row,k], B[k,n], acc)
// rows = flattened (batch*M) = 2048. One block = BM rows x 512 cols,
// 256 threads, each thread owns BM x 2 outputs. A panel staged in LDS
// (broadcast reads, conflict-free); B rows read coalesced and L2/L3-hot.
// ---------------------------------------------------------------------------
__global__ __launch_bounds__(256) void gemm_seq_kernel(const float* __restrict__ A,
                                                       const float* __restrict__ B,
                                                       float* __restrict__ C) {
    __shared__ float As[BM * KDIM];

    const int rowBase = blockIdx.x * BM;            // over 2048 rows
    const float* Ablk = A + (size_t)rowBase * KDIM;

    for (int i = threadIdx.x; i < BM * KDIM; i += 256) {
        As[i] = Ablk[i];
    }
    __syncthreads();

    const int n0 = threadIdx.x;
    const int n1 = threadIdx.x + 256;

    float acc0[BM];
    float acc1[BM];
#pragma unroll
    for (int r = 0; r < BM; ++r) { acc0[r] = 0.0f; acc1[r] = 0.0f; }

    for (int k = 0; k < KDIM; ++k) {
        float b0 = B[k * NDIM + n0];
        float b1 = B[k * NDIM + n1];
#pragma unroll
        for (int r = 0; r < BM; ++r) {
            float a = As[r * KDIM + k];
            acc0[r] = __builtin_fmaf(a, b0, acc0[r]);   // single-rounded FMA
            acc1[r] = __builtin_fmaf(a, b1, acc1[r]);
        }
    }

#pragma unroll
    for (int r = 0; r < BM; ++r) {
        C[(size_t)(rowBase + r) * NDIM + n0] = acc0[r];
        C[(size_t)(rowBase + r) * NDIM + n1] = acc1[r];
    }
}

// ---------------------------------------------------------------------------
// Kernel 4: fp32 words -> pulse bits (float {0,1}). Coalesced writes; the
// 4 MiB C buffer is read broadcast (L1/L2 served).
// ---------------------------------------------------------------------------
__global__ void encode_bits_kernel(const float* __restrict__ vals,
                                   float* __restrict__ bits, int nbits) {
    int g = blockIdx.x * blockDim.x + threadIdx.x;
    if (g >= nbits) return;
    uint32_t u = __float_as_uint(vals[g >> 5]);
    bits[g] = (float)((u >> (g & 31)) & 1u);
}

extern "C" void kernel_launch(void* const* d_in, const int* in_sizes, int n_in,
                              void* d_out, int out_size, void* d_ws, size_t ws_size,
                              hipStream_t stream) {
    const float* Abits = (const float*)d_in[0];   // [4,512,512,32] floats {0,1}
    const float* Bbits = (const float*)d_in[1];   // [512,512,32]
    float* out = (float*)d_out;                   // [4,512,512,32]

    const int nA = in_sizes[0];                   // 33,554,432 bits
    const int nB = in_sizes[1];                   //  8,388,608 bits
    const int elemsA = nA >> 5;                   // 1,048,576 fp32
    const int elemsB = nB >> 5;                   //   262,144 fp32

    // Workspace layout: A_u32 | B_u32 | C_f32  (4 MiB + 1 MiB + 4 MiB = 9 MiB)
    uint32_t* A_u = (uint32_t*)d_ws;
    uint32_t* B_u = A_u + elemsA;
    float*    C_f = (float*)(B_u + elemsB);

    decode_bits_kernel<<<nA / 256, 256, 0, stream>>>(Abits, A_u, nA);
    decode_bits_kernel<<<nB / 256, 256, 0, stream>>>(Bbits, B_u, nB);

    gemm_seq_kernel<<<(BATCH * MDIM) / BM, 256, 0, stream>>>(
        (const float*)A_u, (const float*)B_u, C_f);

    encode_bits_kernel<<<out_size / 256, 256, 0, stream>>>(C_f, out, out_size);
}

// Round 3
// 124.027 us; speedup vs baseline: 1.3865x; 1.3865x over previous
//
#include <hip/hip_runtime.h>
#include <stdint.h>

// Geometry fixed by the reference: A bits [4,512,512,32], B bits [512,512,32]
#define BATCH 4
#define MDIM  512
#define KDIM  512
#define NDIM  512
#define ROWS  (BATCH * MDIM)   // 2048 flattened output rows
#define KC    64               // k-chunk staged per barrier round
#define BROWS 16               // C rows per block
#define BCOLS 256              // C cols per block

// ---------------------------------------------------------------------------
// Decode: pulse bits (float {0,1}, bit0=LSB) -> u32 words. One word per
// thread per iteration via 8 independent float4 loads (128B MLP/thread).
// Values are exactly 0.0f/1.0f, so bit = (__float_as_uint(v)>>29)&1
// (1.0f = 0x3F800000 -> bit29 set). Exact integer op, no FP rounding.
// ---------------------------------------------------------------------------
__global__ __launch_bounds__(256) void decode_words(const float* __restrict__ bits,
                                                    uint32_t* __restrict__ words,
                                                    int nwords) {
    int stride = gridDim.x * blockDim.x;
    for (int w = blockIdx.x * blockDim.x + threadIdx.x; w < nwords; w += stride) {
        const float4* p = (const float4*)(bits + (size_t)w * 32);
        uint32_t u = 0;
#pragma unroll
        for (int i = 0; i < 8; ++i) {
            float4 v = p[i];
            u |= ((__float_as_uint(v.x) >> 29) & 1u) << (4 * i + 0);
            u |= ((__float_as_uint(v.y) >> 29) & 1u) << (4 * i + 1);
            u |= ((__float_as_uint(v.z) >> 29) & 1u) << (4 * i + 2);
            u |= ((__float_as_uint(v.w) >> 29) & 1u) << (4 * i + 3);
        }
        words[w] = u;
    }
}

// ---------------------------------------------------------------------------
// GEMM (exact np.einsum semantics: per output element, single accumulator,
// k ascending, one FMA per step) + fused bit-encode epilogue.
// Block: 16 rows x 256 cols, 256 threads; thread = 1 col, 16 row-accs.
// Per k: 16 A values broadcast from LDS (uniform addr) + 1 B value
// (conflict-free) -> 16 FMAs. B staged with global_load_lds (linear dest),
// A reg-staged with transpose. Epilogue writes 32 bit-floats per output
// (128B contiguous per element).
// ---------------------------------------------------------------------------
__global__ __launch_bounds__(256) void gemm_encode(const float* __restrict__ A,
                                                   const float* __restrict__ B,
                                                   float* __restrict__ outbits) {
    __shared__ float Bs[KC][BCOLS];   // 64 KiB
    __shared__ float As[KC][BROWS];   // 4 KiB

    const int tid = threadIdx.x;
    const int rowBase = blockIdx.x * BROWS;
    const int n0 = blockIdx.y * BCOLS;
    const int n = n0 + tid;

    float acc[BROWS];
#pragma unroll
    for (int r = 0; r < BROWS; ++r) acc[r] = 0.0f;

    for (int k0 = 0; k0 < KDIM; k0 += KC) {
        __syncthreads();   // previous chunk's LDS reads done before overwrite
        // Stage A chunk [KC x BROWS], transposed to k-major.
        {
            int r  = tid >> 4;   // 0..15
            int kq = tid & 15;   // 0..15 (quad of 4 k's)
            float4 av = *(const float4*)(A + (size_t)(rowBase + r) * KDIM + k0 + kq * 4);
            As[kq * 4 + 0][r] = av.x;
            As[kq * 4 + 1][r] = av.y;
            As[kq * 4 + 2][r] = av.z;
            As[kq * 4 + 3][r] = av.w;
        }
        // Stage B chunk [KC x BCOLS] via async global->LDS (16B/lane, linear dest).
#pragma unroll
        for (int it = 0; it < (KC * BCOLS) / (256 * 4); ++it) {   // 16 iters
            int c  = it * 1024 + tid * 4;   // float index within chunk
            int kk = c >> 8;                // /BCOLS
            int j  = c & (BCOLS - 1);
            const float* gsrc = B + (size_t)(k0 + kk) * NDIM + n0 + j;
            __builtin_amdgcn_global_load_lds(
                (const __attribute__((address_space(1))) void*)gsrc,
                (__attribute__((address_space(3))) void*)(&Bs[0][0] + c),
                16, 0, 0);
        }
        __syncthreads();   // drains vmcnt+lgkmcnt: staging complete

#pragma unroll 4
        for (int kk = 0; kk < KC; ++kk) {
            float b = Bs[kk][tid];
            const float4* ap = (const float4*)&As[kk][0];   // uniform addr -> broadcast
            float4 a0 = ap[0], a1 = ap[1], a2 = ap[2], a3 = ap[3];
            acc[0]  = __builtin_fmaf(a0.x, b, acc[0]);
            acc[1]  = __builtin_fmaf(a0.y, b, acc[1]);
            acc[2]  = __builtin_fmaf(a0.z, b, acc[2]);
            acc[3]  = __builtin_fmaf(a0.w, b, acc[3]);
            acc[4]  = __builtin_fmaf(a1.x, b, acc[4]);
            acc[5]  = __builtin_fmaf(a1.y, b, acc[5]);
            acc[6]  = __builtin_fmaf(a1.z, b, acc[6]);
            acc[7]  = __builtin_fmaf(a1.w, b, acc[7]);
            acc[8]  = __builtin_fmaf(a2.x, b, acc[8]);
            acc[9]  = __builtin_fmaf(a2.y, b, acc[9]);
            acc[10] = __builtin_fmaf(a2.z, b, acc[10]);
            acc[11] = __builtin_fmaf(a2.w, b, acc[11]);
            acc[12] = __builtin_fmaf(a3.x, b, acc[12]);
            acc[13] = __builtin_fmaf(a3.y, b, acc[13]);
            acc[14] = __builtin_fmaf(a3.z, b, acc[14]);
            acc[15] = __builtin_fmaf(a3.w, b, acc[15]);
        }
    }

    // Fused encode epilogue: 32 pulse bits per output, 128B contiguous/elem.
#pragma unroll
    for (int r = 0; r < BROWS; ++r) {
        uint32_t u = __float_as_uint(acc[r]);
        float* o = outbits + ((size_t)(rowBase + r) * NDIM + n) * 32;
#pragma unroll
        for (int j = 0; j < 8; ++j) {
            float4 q;
            q.x = (float)((u >> (4 * j + 0)) & 1u);
            q.y = (float)((u >> (4 * j + 1)) & 1u);
            q.z = (float)((u >> (4 * j + 2)) & 1u);
            q.w = (float)((u >> (4 * j + 3)) & 1u);
            *(float4*)(o + 4 * j) = q;
        }
    }
}

extern "C" void kernel_launch(void* const* d_in, const int* in_sizes, int n_in,
                              void* d_out, int out_size, void* d_ws, size_t ws_size,
                              hipStream_t stream) {
    const float* Abits = (const float*)d_in[0];   // [4,512,512,32] floats {0,1}
    const float* Bbits = (const float*)d_in[1];   // [512,512,32]
    float* out = (float*)d_out;                   // [4,512,512,32]

    const int nA = in_sizes[0];                   // 33,554,432 bits
    const int nB = in_sizes[1];                   //  8,388,608 bits
    const int wordsA = nA >> 5;                   // 1,048,576
    const int wordsB = nB >> 5;                   //   262,144

    // Workspace: A_u32 (4 MiB) | B_u32 (1 MiB)
    uint32_t* A_u = (uint32_t*)d_ws;
    uint32_t* B_u = A_u + wordsA;

    decode_words<<<2048, 256, 0, stream>>>(Abits, A_u, wordsA);
    decode_words<<<1024, 256, 0, stream>>>(Bbits, B_u, wordsB);

    dim3 grid(ROWS / BROWS, NDIM / BCOLS);        // (128, 2)
    gemm_encode<<<grid, 256, 0, stream>>>((const float*)A_u, (const float*)B_u, out);
}

// Round 4
// 117.213 us; speedup vs baseline: 1.4671x; 1.0581x over previous
//
#include <hip/hip_runtime.h>
#include <stdint.h>

// Geometry fixed by the reference: A bits [4,512,512,32], B bits [512,512,32]
#define BATCH 4
#define MDIM  512
#define KDIM  512
#define NDIM  512
#define ROWS  (BATCH * MDIM)   // 2048 flattened output rows
#define KC    32               // k-chunk per buffer
#define NCHUNK (KDIM / KC)     // 16
#define BROWS 8                // C rows per block (8 accs/thread)
#define BCOLS 256              // C cols per block (1 col/thread)

// ---------------------------------------------------------------------------
// Decode: pulse bits (float {0,1}, bit0=LSB) -> u32 words. One word per
// thread via 8 independent float4 loads (128B MLP/thread). Values are
// exactly 0.0f/1.0f, so bit = (__float_as_uint(v)>>29)&1. Exact integer op.
// ---------------------------------------------------------------------------
__global__ __launch_bounds__(256) void decode_words(const float* __restrict__ bits,
                                                    uint32_t* __restrict__ words,
                                                    int nwords) {
    int stride = gridDim.x * blockDim.x;
    for (int w = blockIdx.x * blockDim.x + threadIdx.x; w < nwords; w += stride) {
        const float4* p = (const float4*)(bits + (size_t)w * 32);
        uint32_t u = 0;
#pragma unroll
        for (int i = 0; i < 8; ++i) {
            float4 v = p[i];
            u |= ((__float_as_uint(v.x) >> 29) & 1u) << (4 * i + 0);
            u |= ((__float_as_uint(v.y) >> 29) & 1u) << (4 * i + 1);
            u |= ((__float_as_uint(v.z) >> 29) & 1u) << (4 * i + 2);
            u |= ((__float_as_uint(v.w) >> 29) & 1u) << (4 * i + 3);
        }
        words[w] = u;
    }
}

// ---------------------------------------------------------------------------
// GEMM (exact np.einsum semantics: per output element, single accumulator,
// k ascending, one FMA per step) + fused bit-encode epilogue.
// Block: 8 rows x 256 cols, 256 threads; thread = 1 col, 8 row-accs.
// Double-buffered LDS (KC=32): stage chunk t+1 async (global_load_lds,
// linear dests, conflict-free) while computing chunk t; one barrier/chunk.
// Per kk: 1 conflict-free B read + 2 uniform-broadcast float4 A reads
// -> 8 FMAs.
// ---------------------------------------------------------------------------
__global__ __launch_bounds__(256) void gemm_encode(const float* __restrict__ A,
                                                   const float* __restrict__ B,
                                                   float* __restrict__ outbits) {
    __shared__ float Bs[2][KC][BCOLS];   // 64 KiB
    __shared__ float As[2][KC][BROWS];   // 2 KiB

    const int tid = threadIdx.x;
    const int rowBase = blockIdx.x * BROWS;
    const int n0 = blockIdx.y * BCOLS;
    const int n = n0 + tid;

    float acc[BROWS];
#pragma unroll
    for (int r = 0; r < BROWS; ++r) acc[r] = 0.0f;

    // Async stage of one k-chunk into buffer `buf`. All dests are linear in
    // lane order (conflict-free; width x lane contiguous), sources per-lane.
    auto stage = [&](int buf, int k0) {
        // A chunk: 256 floats, lane i -> As[buf] flat offset i (k=i>>3, r=i&7).
        {
            const float* gsrc = A + (size_t)(rowBase + (tid & 7)) * KDIM + k0 + (tid >> 3);
            __builtin_amdgcn_global_load_lds(
                (const __attribute__((address_space(1))) void*)gsrc,
                (__attribute__((address_space(3))) void*)(&As[buf][0][0] + tid),
                4, 0, 0);
        }
        // B chunk [KC x BCOLS] = 32 KiB: 8 iters x 256 lanes x 16B.
#pragma unroll
        for (int it = 0; it < (KC * BCOLS) / (256 * 4); ++it) {
            int c  = it * 1024 + tid * 4;   // float index within chunk
            int kk = c >> 8;                // /BCOLS
            int j  = c & (BCOLS - 1);
            const float* gsrc = B + (size_t)(k0 + kk) * NDIM + n0 + j;
            __builtin_amdgcn_global_load_lds(
                (const __attribute__((address_space(1))) void*)gsrc,
                (__attribute__((address_space(3))) void*)(&Bs[buf][0][0] + c),
                16, 0, 0);
        }
    };

    stage(0, 0);
    __syncthreads();               // drain vmcnt: buffer 0 ready

    int cur = 0;
    for (int t = 0; t < NCHUNK; ++t) {
        if (t + 1 < NCHUNK) stage(cur ^ 1, (t + 1) * KC);   // prefetch next

#pragma unroll 8
        for (int kk = 0; kk < KC; ++kk) {
            float b = Bs[cur][kk][tid];
            const float4* ap = (const float4*)&As[cur][kk][0];  // uniform -> broadcast
            float4 a0 = ap[0], a1 = ap[1];
            acc[0] = __builtin_fmaf(a0.x, b, acc[0]);
            acc[1] = __builtin_fmaf(a0.y, b, acc[1]);
            acc[2] = __builtin_fmaf(a0.z, b, acc[2]);
            acc[3] = __builtin_fmaf(a0.w, b, acc[3]);
            acc[4] = __builtin_fmaf(a1.x, b, acc[4]);
            acc[5] = __builtin_fmaf(a1.y, b, acc[5]);
            acc[6] = __builtin_fmaf(a1.z, b, acc[6]);
            acc[7] = __builtin_fmaf(a1.w, b, acc[7]);
        }
        __syncthreads();           // drains vmcnt (next buf staged) + syncs reads
        cur ^= 1;
    }

    // Fused encode epilogue: 32 pulse bits per output, 128B contiguous/elem.
#pragma unroll
    for (int r = 0; r < BROWS; ++r) {
        uint32_t u = __float_as_uint(acc[r]);
        float* o = outbits + ((size_t)(rowBase + r) * NDIM + n) * 32;
#pragma unroll
        for (int j = 0; j < 8; ++j) {
            float4 q;
            q.x = (float)((u >> (4 * j + 0)) & 1u);
            q.y = (float)((u >> (4 * j + 1)) & 1u);
            q.z = (float)((u >> (4 * j + 2)) & 1u);
            q.w = (float)((u >> (4 * j + 3)) & 1u);
            *(float4*)(o + 4 * j) = q;
        }
    }
}

extern "C" void kernel_launch(void* const* d_in, const int* in_sizes, int n_in,
                              void* d_out, int out_size, void* d_ws, size_t ws_size,
                              hipStream_t stream) {
    const float* Abits = (const float*)d_in[0];   // [4,512,512,32] floats {0,1}
    const float* Bbits = (const float*)d_in[1];   // [512,512,32]
    float* out = (float*)d_out;                   // [4,512,512,32]

    const int nA = in_sizes[0];                   // 33,554,432 bits
    const int nB = in_sizes[1];                   //  8,388,608 bits
    const int wordsA = nA >> 5;                   // 1,048,576
    const int wordsB = nB >> 5;                   //   262,144

    // Workspace: A_u32 (4 MiB) | B_u32 (1 MiB)
    uint32_t* A_u = (uint32_t*)d_ws;
    uint32_t* B_u = A_u + wordsA;

    decode_words<<<wordsA / 256, 256, 0, stream>>>(Abits, A_u, wordsA);
    decode_words<<<wordsB / 256, 256, 0, stream>>>(Bbits, B_u, wordsB);

    dim3 grid(ROWS / BROWS, NDIM / BCOLS);        // (256, 2) = 512 blocks
    gemm_encode<<<grid, 256, 0, stream>>>((const float*)A_u, (const float*)B_u, out);
}

// Round 5
// 111.192 us; speedup vs baseline: 1.5465x; 1.0541x over previous
//
#include <hip/hip_runtime.h>
#include <stdint.h>

// Geometry fixed by the reference: A bits [4,512,512,32], B bits [512,512,32]
#define BATCH 4
#define MDIM  512
#define KDIM  512
#define NDIM  512
#define ROWS  (BATCH * MDIM)   // 2048 flattened output rows
#define BR    4                // C rows per block (4 accs/thread)
#define BCOLS 256              // C cols per block (1 col/thread)

// ---------------------------------------------------------------------------
// Decode (A and B fused in one launch): pulse bits (float {0,1}, bit0=LSB)
// -> u32 words. One word per thread-iter via 8 independent float4 loads
// (128B MLP/thread). Values are exactly 0.0f/1.0f, so
// bit = (__float_as_uint(v)>>29)&1  (1.0f = 0x3F800000). Exact integer op.
// ---------------------------------------------------------------------------
__global__ __launch_bounds__(256) void decode_all(const float* __restrict__ Abits,
                                                  const float* __restrict__ Bbits,
                                                  uint32_t* __restrict__ Au,
                                                  uint32_t* __restrict__ Bu,
                                                  int wordsA, int wordsB) {
    int total = wordsA + wordsB;
    int stride = gridDim.x * blockDim.x;
    for (int w = blockIdx.x * blockDim.x + threadIdx.x; w < total; w += stride) {
        const float* src;
        uint32_t* dst;
        if (w < wordsA) { src = Abits + (size_t)w * 32;            dst = Au + w; }
        else            { src = Bbits + (size_t)(w - wordsA) * 32; dst = Bu + (w - wordsA); }
        const float4* p = (const float4*)src;
        uint32_t u = 0;
#pragma unroll
        for (int i = 0; i < 8; ++i) {
            float4 v = p[i];
            u |= ((__float_as_uint(v.x) >> 29) & 1u) << (4 * i + 0);
            u |= ((__float_as_uint(v.y) >> 29) & 1u) << (4 * i + 1);
            u |= ((__float_as_uint(v.z) >> 29) & 1u) << (4 * i + 2);
            u |= ((__float_as_uint(v.w) >> 29) & 1u) << (4 * i + 3);
        }
        *dst = u;
    }
}

// ---------------------------------------------------------------------------
// LDS-free GEMM (exact np.einsum semantics: per output element, single
// accumulator, k ascending, one FMA per step) + fused bit-encode epilogue.
// Block: 4 rows x 256 cols, 256 threads; thread = 1 col, 4 row-accs.
// A loads are wave-uniform (blockIdx + loop constants only) -> scalar/L1.
// B loads are lane-coalesced (thread n reads B[k][n]); B is 1 MiB ->
// L2/L1-resident. No LDS, no barriers; 1024 blocks = 4 waves/SIMD.
// ---------------------------------------------------------------------------
__global__ __launch_bounds__(256) void gemm_encode(const float* __restrict__ A,
                                                   const float* __restrict__ B,
                                                   float* __restrict__ outbits) {
    const int tid = threadIdx.x;
    const int rowBase = blockIdx.x * BR;
    const int n = blockIdx.y * BCOLS + tid;

    float acc[BR];
#pragma unroll
    for (int r = 0; r < BR; ++r) acc[r] = 0.0f;

    const float* Bcol = B + n;
    const float* Arow = A + (size_t)rowBase * KDIM;

    for (int k0 = 0; k0 < KDIM; k0 += 4) {
        // 4 coalesced B values (stride NDIM across k)
        float b0 = Bcol[(size_t)(k0 + 0) * NDIM];
        float b1 = Bcol[(size_t)(k0 + 1) * NDIM];
        float b2 = Bcol[(size_t)(k0 + 2) * NDIM];
        float b3 = Bcol[(size_t)(k0 + 3) * NDIM];
        // 4 wave-uniform A float4s (one per row)
        float4 a[BR];
#pragma unroll
        for (int r = 0; r < BR; ++r)
            a[r] = *(const float4*)(Arow + (size_t)r * KDIM + k0);
        // k ascending within the group; one FMA per step per element.
#pragma unroll
        for (int r = 0; r < BR; ++r) {
            acc[r] = __builtin_fmaf(a[r].x, b0, acc[r]);
            acc[r] = __builtin_fmaf(a[r].y, b1, acc[r]);
            acc[r] = __builtin_fmaf(a[r].z, b2, acc[r]);
            acc[r] = __builtin_fmaf(a[r].w, b3, acc[r]);
        }
    }

    // Fused encode epilogue: 32 pulse bits per output, 128B contiguous/elem.
#pragma unroll
    for (int r = 0; r < BR; ++r) {
        uint32_t u = __float_as_uint(acc[r]);
        float* o = outbits + ((size_t)(rowBase + r) * NDIM + n) * 32;
#pragma unroll
        for (int j = 0; j < 8; ++j) {
            float4 q;
            q.x = (float)((u >> (4 * j + 0)) & 1u);
            q.y = (float)((u >> (4 * j + 1)) & 1u);
            q.z = (float)((u >> (4 * j + 2)) & 1u);
            q.w = (float)((u >> (4 * j + 3)) & 1u);
            *(float4*)(o + 4 * j) = q;
        }
    }
}

extern "C" void kernel_launch(void* const* d_in, const int* in_sizes, int n_in,
                              void* d_out, int out_size, void* d_ws, size_t ws_size,
                              hipStream_t stream) {
    const float* Abits = (const float*)d_in[0];   // [4,512,512,32] floats {0,1}
    const float* Bbits = (const float*)d_in[1];   // [512,512,32]
    float* out = (float*)d_out;                   // [4,512,512,32]

    const int nA = in_sizes[0];                   // 33,554,432 bits
    const int nB = in_sizes[1];                   //  8,388,608 bits
    const int wordsA = nA >> 5;                   // 1,048,576
    const int wordsB = nB >> 5;                   //   262,144

    // Workspace: A_u32 (4 MiB) | B_u32 (1 MiB)
    uint32_t* A_u = (uint32_t*)d_ws;
    uint32_t* B_u = A_u + wordsA;

    decode_all<<<2048, 256, 0, stream>>>(Abits, Bbits, A_u, B_u, wordsA, wordsB);

    dim3 grid(ROWS / BR, NDIM / BCOLS);           // (512, 2) = 1024 blocks
    gemm_encode<<<grid, 256, 0, stream>>>((const float*)A_u, (const float*)B_u, out);
}

// Round 6
// 87.203 us; speedup vs baseline: 1.9720x; 1.2751x over previous
//
#include <hip/hip_runtime.h>
#include <stdint.h>

// Geometry fixed by the reference: A bits [4,512,512,32], B bits [512,512,32]
#define BATCH 4
#define MDIM  512
#define KDIM  512
#define NDIM  512
#define ROWS  (BATCH * MDIM)   // 2048 flattened output rows
#define BR    4                // C rows per block (4 accs/thread)
#define BCOLS 256              // C cols per block (1 col/thread)

// Spread 8 bits so bit i lands at position 4*i (exact integer op).
__device__ __forceinline__ uint32_t spread4(uint32_t x) {
    x = (x | (x << 12)) & 0x000F000Fu;
    x = (x | (x << 6))  & 0x03030303u;
    x = (x | (x << 3))  & 0x11111111u;
    return x;
}

// ---------------------------------------------------------------------------
// Decode: pulse bits (float {0,1}, bit0=LSB) -> u32 words, fully coalesced.
// Per wave-iteration: 64 lanes read 1 KiB CONTIGUOUS (uint4/lane) = 8 words.
// Bit of value v is bit29 of its IEEE pattern (1.0f = 0x3F800000). Four
// __ballot's collect the wave's 256 bits; lanes with (lane&7)==0 assemble
// word g = lane>>3 from ballot bytes via 1->4 bit spread. Integer-exact.
// ---------------------------------------------------------------------------
__global__ __launch_bounds__(256) void decode_all(const float* __restrict__ Abits,
                                                  const float* __restrict__ Bbits,
                                                  uint32_t* __restrict__ Au,
                                                  uint32_t* __restrict__ Bu,
                                                  int wordsA, int wordsB) {
    const int lane = threadIdx.x & 63;
    const int waveId = (blockIdx.x * blockDim.x + threadIdx.x) >> 6;
    const int totalWaves = (gridDim.x * blockDim.x) >> 6;
    const int totalWords = wordsA + wordsB;   // both multiples of 8
    const int sh = lane & 56;                 // 8*(lane>>3)

    for (int wb = waveId * 8; wb < totalWords; wb += totalWaves * 8) {
        const float* src;
        uint32_t* dst;
        if (wb < wordsA) { src = Abits + (size_t)wb * 32;            dst = Au + wb; }
        else             { src = Bbits + (size_t)(wb - wordsA) * 32; dst = Bu + (wb - wordsA); }

        uint4 v = ((const uint4*)src)[lane];          // wave: 1 KiB contiguous
        unsigned long long m0 = __ballot((v.x >> 29) & 1u);
        unsigned long long m1 = __ballot((v.y >> 29) & 1u);
        unsigned long long m2 = __ballot((v.z >> 29) & 1u);
        unsigned long long m3 = __ballot((v.w >> 29) & 1u);

        if ((lane & 7) == 0) {
            uint32_t w = (spread4((uint32_t)(m0 >> sh) & 0xFFu) << 0)
                       | (spread4((uint32_t)(m1 >> sh) & 0xFFu) << 1)
                       | (spread4((uint32_t)(m2 >> sh) & 0xFFu) << 2)
                       | (spread4((uint32_t)(m3 >> sh) & 0xFFu) << 3);
            dst[lane >> 3] = w;
        }
    }
}

// ---------------------------------------------------------------------------
// LDS-free GEMM k-loop (exact np.einsum semantics: per output element, single
// accumulator, k ascending, one FMA per step) + LDS-transposed coalesced
// bit-encode epilogue.
// Block: 4 rows x 256 cols, 256 threads; thread = 1 col, 4 row-accs.
// A loads wave-uniform (scalar path); B loads lane-coalesced, L1/L2-resident.
// Epilogue: accs -> 4 KiB LDS, 1 barrier, then 128 KiB written with
// consecutive-lane float4 stores (1 KiB/wave/instr); LDS reads are 8-lane
// broadcasts (conflict-free).
// ---------------------------------------------------------------------------
__global__ __launch_bounds__(256) void gemm_encode(const float* __restrict__ A,
                                                   const float* __restrict__ B,
                                                   float* __restrict__ outbits) {
    __shared__ uint32_t Us[BR][BCOLS];   // 4 KiB

    const int tid = threadIdx.x;
    const int rowBase = blockIdx.x * BR;
    const int n0 = blockIdx.y * BCOLS;
    const int n = n0 + tid;

    float acc[BR];
#pragma unroll
    for (int r = 0; r < BR; ++r) acc[r] = 0.0f;

    const float* Bcol = B + n;
    const float* Arow = A + (size_t)rowBase * KDIM;

    for (int k0 = 0; k0 < KDIM; k0 += 4) {
        float b0 = Bcol[(size_t)(k0 + 0) * NDIM];
        float b1 = Bcol[(size_t)(k0 + 1) * NDIM];
        float b2 = Bcol[(size_t)(k0 + 2) * NDIM];
        float b3 = Bcol[(size_t)(k0 + 3) * NDIM];
        float4 a[BR];
#pragma unroll
        for (int r = 0; r < BR; ++r)
            a[r] = *(const float4*)(Arow + (size_t)r * KDIM + k0);
#pragma unroll
        for (int r = 0; r < BR; ++r) {
            acc[r] = __builtin_fmaf(a[r].x, b0, acc[r]);
            acc[r] = __builtin_fmaf(a[r].y, b1, acc[r]);
            acc[r] = __builtin_fmaf(a[r].z, b2, acc[r]);
            acc[r] = __builtin_fmaf(a[r].w, b3, acc[r]);
        }
    }

    // ---- epilogue: transpose through LDS, then coalesced bit stores ----
#pragma unroll
    for (int r = 0; r < BR; ++r) Us[r][tid] = __float_as_uint(acc[r]);
    __syncthreads();

    float* oBase = outbits + ((size_t)rowBase * NDIM + n0) * 32;
    const int b = (tid & 7) * 4;
#pragma unroll
    for (int r = 0; r < BR; ++r) {
        float* o = oBase + (size_t)r * NDIM * 32;
#pragma unroll
        for (int it = 0; it < 8; ++it) {
            uint32_t u = Us[r][it * 32 + (tid >> 3)];   // 8-lane broadcast
            float4 q;
            q.x = (float)((u >> (b + 0)) & 1u);
            q.y = (float)((u >> (b + 1)) & 1u);
            q.z = (float)((u >> (b + 2)) & 1u);
            q.w = (float)((u >> (b + 3)) & 1u);
            *(float4*)(o + it * 1024 + tid * 4) = q;    // lanes contiguous
        }
    }
}

extern "C" void kernel_launch(void* const* d_in, const int* in_sizes, int n_in,
                              void* d_out, int out_size, void* d_ws, size_t ws_size,
                              hipStream_t stream) {
    const float* Abits = (const float*)d_in[0];   // [4,512,512,32] floats {0,1}
    const float* Bbits = (const float*)d_in[1];   // [512,512,32]
    float* out = (float*)d_out;                   // [4,512,512,32]

    const int nA = in_sizes[0];                   // 33,554,432 bits
    const int nB = in_sizes[1];                   //  8,388,608 bits
    const int wordsA = nA >> 5;                   // 1,048,576
    const int wordsB = nB >> 5;                   //   262,144

    // Workspace: A_u32 (4 MiB) | B_u32 (1 MiB)
    uint32_t* A_u = (uint32_t*)d_ws;
    uint32_t* B_u = A_u + wordsA;

    decode_all<<<2048, 256, 0, stream>>>(Abits, Bbits, A_u, B_u, wordsA, wordsB);

    dim3 grid(ROWS / BR, NDIM / BCOLS);           // (512, 2) = 1024 blocks
    gemm_encode<<<grid, 256, 0, stream>>>((const float*)A_u, (const float*)B_u, out);
}